// Round 5
// baseline (806.497 us; speedup 1.0000x reference)
//
#include <hip/hip_runtime.h>

// SlotAttentionSmolensky on MI355X (gfx950).
// R0: baseline pass, 776us. attn_pass 133us x3: VALUBusy 24%, Occ 44% ->
//     memory-latency-bound from low TLP (grid 1024x256 = 50% thread capacity).
// R1: launch_bounds(256,3)+prefetch -> post-timing divergence (0.097) + slower
//     (scratch spill). REVERTED.
// R4: R0 attn body exactly, but 512 thr/block (8 waves x 16 j) -> 100% thread
//     capacity for latency hiding. Scratch aliased into dead x16 region
//     (ws footprint 212->193 MiB; removes OOB-tail risk).
// EPS*Vsum term dropped (<=1e-6 abs, analyzed); N*EPS kept in denominator.

#define B_ 32
#define N_ 4096
#define H_ 4
#define NF_ 8
#define SH_ 32
#define SCALE_ 0.125f
#define EPS_ 1e-8f

typedef __bf16 bf16x8 __attribute__((ext_vector_type(8)));
typedef float f32x4 __attribute__((ext_vector_type(4)));

__device__ __forceinline__ unsigned short f2bf(float f) {
  unsigned int u = __builtin_bit_cast(unsigned int, f);
  u += 0x7fffu + ((u >> 16) & 1u);
  return (unsigned short)(u >> 16);
}
__device__ __forceinline__ float bflo(unsigned int u) {
  return __builtin_bit_cast(float, u << 16);
}
__device__ __forceinline__ float bfhi(unsigned int u) {
  return __builtin_bit_cast(float, u & 0xffff0000u);
}
__device__ __forceinline__ float b2f(unsigned short s) {
  return __builtin_bit_cast(float, ((unsigned int)s) << 16);
}

#define GLDS16(gp, lp)                                                        \
  __builtin_amdgcn_global_load_lds(                                           \
      (const __attribute__((address_space(1))) void*)(gp),                    \
      (__attribute__((address_space(3))) void*)(lp), 16, 0, 0)

// ---------------- prep: weight staging ----------------
__global__ void __launch_bounds__(256) prep_kernel(
    const float* __restrict__ Wq, const float* __restrict__ Wk,
    const float* __restrict__ Wv, const float* __restrict__ Wih,
    const float* __restrict__ Whh, unsigned short* __restrict__ Bkv,
    float* __restrict__ Wqt, unsigned short* __restrict__ Wcat) {
  const int idx = blockIdx.x * 256 + threadIdx.x;
  if (idx < 131072) {
    const int n = idx >> 8, k = idx & 255;
    const float v = (n < 256) ? Wk[n * 256 + k] : Wv[(n - 256) * 256 + k];
    Bkv[idx] = f2bf(v);
  } else if (idx < 196608) {
    const int r = idx - 131072;
    const int k = r >> 8, d = r & 255;
    Wqt[r] = Wq[d * 256 + k];
  } else if (idx < 589824) {
    const int r = idx - 196608;
    const int k = r / 1536, o = r - k * 1536;
    const float v = (o < 768) ? Wih[o * 256 + k] : Whh[(o - 768) * 256 + k];
    Wcat[r] = f2bf(v);
  }
}

// ---------------- LN of inputs -> x bf16 ----------------
__global__ void __launch_bounds__(256) ln_in_kernel(
    const float* __restrict__ in, const float* __restrict__ g,
    const float* __restrict__ bb, unsigned short* __restrict__ x16) {
  const size_t row = (size_t)blockIdx.x * 4 + (threadIdx.x >> 6);
  const int lane = threadIdx.x & 63;
  const float4 xv = *(const float4*)(in + row * 256 + lane * 4);
  float s = xv.x + xv.y + xv.z + xv.w;
  float sq = xv.x * xv.x + xv.y * xv.y + xv.z * xv.z + xv.w * xv.w;
#pragma unroll
  for (int m = 1; m < 64; m <<= 1) {
    s += __shfl_xor(s, m);
    sq += __shfl_xor(sq, m);
  }
  const float mean = s * (1.f / 256.f);
  const float var = sq * (1.f / 256.f) - mean * mean;
  const float rstd = rsqrtf(var + 1e-5f);
  const float4 gv = *(const float4*)(g + lane * 4);
  const float4 bv = *(const float4*)(bb + lane * 4);
  ushort4 o;
  o.x = f2bf((xv.x - mean) * rstd * gv.x + bv.x);
  o.y = f2bf((xv.y - mean) * rstd * gv.y + bv.y);
  o.z = f2bf((xv.z - mean) * rstd * gv.z + bv.z);
  o.w = f2bf((xv.w - mean) * rstd * gv.w + bv.w);
  *(ushort4*)(x16 + row * 256 + lane * 4) = o;
}

// ---------------- K/V projection GEMM (m97-style 128x128, BK=64) ----------------
__global__ void __launch_bounds__(256) kv_gemm(
    const unsigned short* __restrict__ x16, const unsigned short* __restrict__ Bkv,
    unsigned short* __restrict__ KV) {
  __shared__ __align__(16) unsigned short As[128 * 64];
  __shared__ __align__(16) unsigned short Bs[128 * 64];
  const int m0 = blockIdx.x * 128;
  const int n0 = blockIdx.y * 128;
  const int t = threadIdx.x;
  const int lane = t & 63, wv = t >> 6;
  const int wm = (wv & 1) * 64, wn = (wv >> 1) * 64;
  const int l15 = lane & 15, l4 = lane >> 4;
  f32x4 acc[4][4];
#pragma unroll
  for (int mi = 0; mi < 4; ++mi)
#pragma unroll
    for (int ni = 0; ni < 4; ++ni) {
      acc[mi][ni][0] = 0.f; acc[mi][ni][1] = 0.f;
      acc[mi][ni][2] = 0.f; acc[mi][ni][3] = 0.f;
    }
  const int sr = t >> 3, sc = t & 7;
  for (int kk = 0; kk < 4; ++kk) {
    const int kb = kk * 64;
#pragma unroll
    for (int i = 0; i < 4; ++i) {
      const unsigned short* ga = x16 + (size_t)(m0 + i * 32 + sr) * 256 + kb + sc * 8;
      GLDS16(ga, &As[(i * 32 + sr) * 64 + sc * 8]);
    }
#pragma unroll
    for (int i = 0; i < 4; ++i) {
      const unsigned short* gb = Bkv + (size_t)(n0 + i * 32 + sr) * 256 + kb + sc * 8;
      GLDS16(gb, &Bs[(i * 32 + sr) * 64 + sc * 8]);
    }
    asm volatile("s_waitcnt vmcnt(0)" ::: "memory");
    __syncthreads();
#pragma unroll
    for (int kc = 0; kc < 2; ++kc) {
      bf16x8 af[4], bfr[4];
#pragma unroll
      for (int mi = 0; mi < 4; ++mi)
        af[mi] = *(const bf16x8*)&As[(wm + mi * 16 + l15) * 64 + kc * 32 + l4 * 8];
#pragma unroll
      for (int ni = 0; ni < 4; ++ni)
        bfr[ni] = *(const bf16x8*)&Bs[(wn + ni * 16 + l15) * 64 + kc * 32 + l4 * 8];
#pragma unroll
      for (int mi = 0; mi < 4; ++mi)
#pragma unroll
        for (int ni = 0; ni < 4; ++ni)
          acc[mi][ni] = __builtin_amdgcn_mfma_f32_16x16x32_bf16(
              af[mi], bfr[ni], acc[mi][ni], 0, 0, 0);
    }
    __syncthreads();
  }
#pragma unroll
  for (int mi = 0; mi < 4; ++mi) {
#pragma unroll
    for (int r = 0; r < 4; ++r) {
      const int gm = m0 + wm + mi * 16 + l4 * 4 + r;
      unsigned short* dst = KV + (size_t)gm * 512 + n0 + wn + l15;
#pragma unroll
      for (int ni = 0; ni < 4; ++ni) dst[ni * 16] = f2bf(acc[mi][ni][r]);
    }
  }
}

// ---------------- q projection: LN(fillers) @ Wq^T ----------------
__global__ void __launch_bounds__(256) qproj_kernel(
    const float* __restrict__ fill, const float* __restrict__ Wqt,
    const float* __restrict__ g, const float* __restrict__ bb,
    float* __restrict__ qbuf) {
  const int bi = blockIdx.x;  // b*8 + i
  const int t = threadIdx.x;
  const int wv = t >> 6, lane = t & 63;
  __shared__ float f[256];
  __shared__ float red[8];
  const float x = fill[bi * 256 + t];
  float s = x, sq = x * x;
#pragma unroll
  for (int m = 1; m < 64; m <<= 1) {
    s += __shfl_xor(s, m);
    sq += __shfl_xor(sq, m);
  }
  if (lane == 0) {
    red[wv] = s;
    red[4 + wv] = sq;
  }
  __syncthreads();
  const float S = red[0] + red[1] + red[2] + red[3];
  const float SQ = red[4] + red[5] + red[6] + red[7];
  const float mean = S * (1.f / 256.f);
  const float var = SQ * (1.f / 256.f) - mean * mean;
  const float rstd = rsqrtf(var + 1e-5f);
  f[t] = (x - mean) * rstd * g[t] + bb[t];
  __syncthreads();
  float acc = 0.f;
  for (int k = 0; k < 256; ++k) acc = fmaf(f[k], Wqt[k * 256 + t], acc);
  qbuf[(size_t)(bi * 4 + (t >> 6)) * 64 + (t & 63)] = acc;
}

// ---------------- attention pass: dots + inverted softmax + update accum ----------------
// R4: R0 body, but 512 threads (8 waves x 16 j) for 100% thread-capacity TLP.
__global__ void attn_pass(
    const unsigned short* __restrict__ KV, const float* __restrict__ qbuf,
    float* __restrict__ partials, float* __restrict__ attn_out, int write_attn) {
  const int bid = blockIdx.x;
  const int b = bid >> 5, c = bid & 31;  // 32 chunks of 128 j per batch
  const int t = threadIdx.x;
  const int wv = t >> 6, lane = t & 63;  // 8 waves
  const int sh = lane & 31, half = lane >> 5;  // sh = i*4+h ; half = d-half
  const int h = sh & 3;

  float qr[32];
  {
    const float* qp = qbuf + (size_t)(b * 32 + sh) * 64 + half * 32;
#pragma unroll
    for (int x = 0; x < 8; ++x) {
      const float4 v = *(const float4*)(qp + x * 4);
      qr[x * 4 + 0] = v.x; qr[x * 4 + 1] = v.y;
      qr[x * 4 + 2] = v.z; qr[x * 4 + 3] = v.w;
    }
  }
  float upd[32];
#pragma unroll
  for (int x = 0; x < 32; ++x) upd[x] = 0.f;
  float ssum = 0.f;

  const int j0 = c * 128 + wv * 16;  // 16 j per wave
  const unsigned short* rowp = KV + ((size_t)b * N_ + j0) * 512;

  for (int jj = 0; jj < 16; ++jj) {
    const unsigned short* kp = rowp + jj * 512 + h * 64 + half * 32;
    uint4 kw[4], vw[4];
#pragma unroll
    for (int x = 0; x < 4; ++x) kw[x] = *(const uint4*)(kp + x * 8);
#pragma unroll
    for (int x = 0; x < 4; ++x) vw[x] = *(const uint4*)(kp + 256 + x * 8);
    float dot = 0.f;
#pragma unroll
    for (int x = 0; x < 4; ++x) {
      dot = fmaf(qr[x * 8 + 0], bflo(kw[x].x), dot);
      dot = fmaf(qr[x * 8 + 1], bfhi(kw[x].x), dot);
      dot = fmaf(qr[x * 8 + 2], bflo(kw[x].y), dot);
      dot = fmaf(qr[x * 8 + 3], bfhi(kw[x].y), dot);
      dot = fmaf(qr[x * 8 + 4], bflo(kw[x].z), dot);
      dot = fmaf(qr[x * 8 + 5], bfhi(kw[x].z), dot);
      dot = fmaf(qr[x * 8 + 6], bflo(kw[x].w), dot);
      dot = fmaf(qr[x * 8 + 7], bfhi(kw[x].w), dot);
    }
    dot += __shfl_xor(dot, 32);  // combine d-halves
    const float logit = dot * SCALE_;
    float mx = logit;
#pragma unroll
    for (int m = 1; m <= 16; m <<= 1) mx = fmaxf(mx, __shfl_xor(mx, m));
    const float e = __expf(logit - mx);
    float se = e;
#pragma unroll
    for (int m = 1; m <= 16; m <<= 1) se += __shfl_xor(se, m);
    const float attn = e / se;
    ssum += attn;
#pragma unroll
    for (int x = 0; x < 4; ++x) {
      upd[x * 8 + 0] = fmaf(attn, bflo(vw[x].x), upd[x * 8 + 0]);
      upd[x * 8 + 1] = fmaf(attn, bfhi(vw[x].x), upd[x * 8 + 1]);
      upd[x * 8 + 2] = fmaf(attn, bflo(vw[x].y), upd[x * 8 + 2]);
      upd[x * 8 + 3] = fmaf(attn, bfhi(vw[x].y), upd[x * 8 + 3]);
      upd[x * 8 + 4] = fmaf(attn, bflo(vw[x].z), upd[x * 8 + 4]);
      upd[x * 8 + 5] = fmaf(attn, bfhi(vw[x].z), upd[x * 8 + 5]);
      upd[x * 8 + 6] = fmaf(attn, bflo(vw[x].w), upd[x * 8 + 6]);
      upd[x * 8 + 7] = fmaf(attn, bfhi(vw[x].w), upd[x * 8 + 7]);
    }
    if (write_attn) {
      float hs = attn;
      hs += __shfl_xor(hs, 1);
      hs += __shfl_xor(hs, 2);  // sum over h (low 2 bits of sh)
      if ((lane & 3) == 0 && half == 0)
        attn_out[((size_t)b * NF_ + (sh >> 2)) * N_ + j0 + jj] = hs * 0.25f;
    }
  }

  // block-level combine of the 8 waves' partials
  __shared__ float uacc[SH_ * 64];
  __shared__ float sacc[SH_];
  for (int x = t; x < SH_ * 64; x += 512) uacc[x] = 0.f;
  if (t < SH_) sacc[t] = 0.f;
  __syncthreads();
  for (int w = 0; w < 8; ++w) {
    if (wv == w) {
#pragma unroll
      for (int x = 0; x < 32; ++x) uacc[sh * 64 + half * 32 + x] += upd[x];
      if (half == 0) sacc[sh] += ssum;
    }
    __syncthreads();
  }
  float* P = partials + (size_t)bid * 2080;
  for (int x = t; x < 2048; x += 512) P[x] = uacc[x];
  if (t < 32) P[2048 + t] = sacc[t];
}

// ---------------- GRU: partial-reduce + updates + GEMV + gates ----------------
__global__ void __launch_bounds__(256) gru_kernel(
    const float* __restrict__ partials, const float* __restrict__ prev,
    const unsigned short* __restrict__ Wcat, const float* __restrict__ bih,
    const float* __restrict__ bhh, float* __restrict__ out) {
  const int bi = blockIdx.x;  // b*8 + i
  const int b = bi >> 3;
  const int t = threadIdx.x;
  const int h = t >> 6;
  const int sh = (bi & 7) * 4 + h;
  __shared__ float u[256], pv[256];
  float raw = 0.f, s = 0.f;
  for (int cc = 0; cc < 32; ++cc) {
    const float* Pp = partials + (size_t)(b * 32 + cc) * 2080;
    raw += Pp[sh * 64 + (t & 63)];
    s += Pp[2048 + sh];
  }
  const float uu = raw / (s + (float)N_ * EPS_);
  u[t] = uu;
  pv[t] = prev[bi * 256 + t];
  __syncthreads();
  float a0 = bih[t], a1 = bih[256 + t], a2 = bih[512 + t];
  float a3 = bhh[t], a4 = bhh[256 + t], a5 = bhh[512 + t];
  for (int k = 0; k < 256; ++k) {
    const float uk = u[k], pk = pv[k];
    const unsigned short* wr = Wcat + k * 1536;
    a0 = fmaf(uk, b2f(wr[t]), a0);
    a1 = fmaf(uk, b2f(wr[256 + t]), a1);
    a2 = fmaf(uk, b2f(wr[512 + t]), a2);
    a3 = fmaf(pk, b2f(wr[768 + t]), a3);
    a4 = fmaf(pk, b2f(wr[1024 + t]), a4);
    a5 = fmaf(pk, b2f(wr[1280 + t]), a5);
  }
  const float r = 1.f / (1.f + __expf(-(a0 + a3)));
  const float z = 1.f / (1.f + __expf(-(a1 + a4)));
  const float n = tanhf(a2 + r * a5);
  out[bi * 256 + t] = (1.f - z) * n + z * pv[t];
}

extern "C" void kernel_launch(void* const* d_in, const int* in_sizes, int n_in,
                              void* d_out, int out_size, void* d_ws, size_t ws_size,
                              hipStream_t stream) {
  (void)in_sizes; (void)n_in; (void)out_size; (void)ws_size;
  const float* inputs = (const float*)d_in[0];
  const float* cond = (const float*)d_in[1];
  const float* Wq = (const float*)d_in[2];
  const float* Wk = (const float*)d_in[3];
  const float* Wv = (const float*)d_in[4];
  const float* Wih = (const float*)d_in[5];
  const float* Whh = (const float*)d_in[6];
  const float* bih = (const float*)d_in[7];
  const float* bhh = (const float*)d_in[8];
  const float* lng = (const float*)d_in[9];
  const float* lnb = (const float*)d_in[10];
  const float* lfg = (const float*)d_in[11];
  const float* lfb = (const float*)d_in[12];
  float* out = (float*)d_out;

  char* ws = (char*)d_ws;
  unsigned short* Bkv = (unsigned short*)(ws);                      // 256 KiB
  float* Wqt = (float*)(ws + 262144);                               // 256 KiB
  unsigned short* Wcat = (unsigned short*)(ws + 524288);            // 768 KiB
  unsigned short* x16 = (unsigned short*)(ws + 1310720);            // 64 MiB
  unsigned short* KV = (unsigned short*)(ws + 1310720 + 67108864);  // 128 MiB
  // Scratch aliased into x16's region (x16 dead after kv_gemm; these live after).
  float* qbuf = (float*)(ws + 1310720);                             // 256 KiB
  float* fillA = qbuf + 65536;                                      // 256 KiB
  float* fillB = fillA + 65536;                                     // 256 KiB
  float* partials = fillB + 65536;                                  // 8.5 MiB (< 64 MiB region)

  hipLaunchKernelGGL(prep_kernel, dim3(2304), dim3(256), 0, stream,
                     Wq, Wk, Wv, Wih, Whh, Bkv, Wqt, Wcat);
  hipLaunchKernelGGL(ln_in_kernel, dim3(32768), dim3(256), 0, stream,
                     inputs, lng, lnb, x16);
  hipLaunchKernelGGL(kv_gemm, dim3(1024, 4), dim3(256), 0, stream, x16, Bkv, KV);

  const float* src = cond;
  float* attn_out = out + 65536;
  for (int it = 0; it < 3; ++it) {
    float* dst = (it == 0) ? fillA : (it == 1) ? fillB : out;  // last iter -> slots
    hipLaunchKernelGGL(qproj_kernel, dim3(256), dim3(256), 0, stream,
                       src, Wqt, lfg, lfb, qbuf);
    hipLaunchKernelGGL(attn_pass, dim3(1024), dim3(512), 0, stream,
                       KV, qbuf, partials, attn_out, (it == 2) ? 1 : 0);
    hipLaunchKernelGGL(gru_kernel, dim3(256), dim3(256), 0, stream,
                       partials, src, Wcat, bih, bhh, dst);
    src = dst;
  }
}

// Round 6
// 632.917 us; speedup vs baseline: 1.2743x; 1.2743x over previous
//
#include <hip/hip_runtime.h>

// SlotAttentionSmolensky on MI355X (gfx950).
// R0: 776us baseline. attn_pass 133us x3, VALUBusy 24%, occ 44%.
// R4: TLP doubling -> no change (142us) => per-wave serial dot + 11 shuffles/j
//     is the structural floor, not occupancy. Post-timing fixed by ws aliasing.
// R5: MFMA attention. qproj emits zero-padded qtil [b][32][256] bf16;
//     dots = qtil @ K^T via mfma_16x16x32 (KV already [j][d] = B^T layout);
//     softmax over sh in MFMA C-layout (2 shuffles/16 cols vs 11/col);
//     P->LDS bf16; V-accum reads P (no shuffles, no dot chain);
//     uacc stride 65 kills the 64-way combine bank conflict.
// EPS*Vsum dropped (<=1e-6 abs); N*EPS kept in denominator.

#define B_ 32
#define N_ 4096
#define H_ 4
#define NF_ 8
#define SH_ 32
#define SCALE_ 0.125f
#define EPS_ 1e-8f

typedef __bf16 bf16x8 __attribute__((ext_vector_type(8)));
typedef float f32x4 __attribute__((ext_vector_type(4)));

__device__ __forceinline__ unsigned short f2bf(float f) {
  unsigned int u = __builtin_bit_cast(unsigned int, f);
  u += 0x7fffu + ((u >> 16) & 1u);
  return (unsigned short)(u >> 16);
}
__device__ __forceinline__ float bflo(unsigned int u) {
  return __builtin_bit_cast(float, u << 16);
}
__device__ __forceinline__ float bfhi(unsigned int u) {
  return __builtin_bit_cast(float, u & 0xffff0000u);
}
__device__ __forceinline__ float b2f(unsigned short s) {
  return __builtin_bit_cast(float, ((unsigned int)s) << 16);
}

#define GLDS16(gp, lp)                                                        \
  __builtin_amdgcn_global_load_lds(                                           \
      (const __attribute__((address_space(1))) void*)(gp),                    \
      (__attribute__((address_space(3))) void*)(lp), 16, 0, 0)

// ---------------- prep: weight staging ----------------
__global__ void __launch_bounds__(256) prep_kernel(
    const float* __restrict__ Wq, const float* __restrict__ Wk,
    const float* __restrict__ Wv, const float* __restrict__ Wih,
    const float* __restrict__ Whh, unsigned short* __restrict__ Bkv,
    float* __restrict__ Wqt, unsigned short* __restrict__ Wcat) {
  const int idx = blockIdx.x * 256 + threadIdx.x;
  if (idx < 131072) {
    const int n = idx >> 8, k = idx & 255;
    const float v = (n < 256) ? Wk[n * 256 + k] : Wv[(n - 256) * 256 + k];
    Bkv[idx] = f2bf(v);
  } else if (idx < 196608) {
    const int r = idx - 131072;
    const int k = r >> 8, d = r & 255;
    Wqt[r] = Wq[d * 256 + k];
  } else if (idx < 589824) {
    const int r = idx - 196608;
    const int k = r / 1536, o = r - k * 1536;
    const float v = (o < 768) ? Wih[o * 256 + k] : Whh[(o - 768) * 256 + k];
    Wcat[r] = f2bf(v);
  }
}

// ---------------- LN of inputs -> x bf16 ----------------
__global__ void __launch_bounds__(256) ln_in_kernel(
    const float* __restrict__ in, const float* __restrict__ g,
    const float* __restrict__ bb, unsigned short* __restrict__ x16) {
  const size_t row = (size_t)blockIdx.x * 4 + (threadIdx.x >> 6);
  const int lane = threadIdx.x & 63;
  const float4 xv = *(const float4*)(in + row * 256 + lane * 4);
  float s = xv.x + xv.y + xv.z + xv.w;
  float sq = xv.x * xv.x + xv.y * xv.y + xv.z * xv.z + xv.w * xv.w;
#pragma unroll
  for (int m = 1; m < 64; m <<= 1) {
    s += __shfl_xor(s, m);
    sq += __shfl_xor(sq, m);
  }
  const float mean = s * (1.f / 256.f);
  const float var = sq * (1.f / 256.f) - mean * mean;
  const float rstd = rsqrtf(var + 1e-5f);
  const float4 gv = *(const float4*)(g + lane * 4);
  const float4 bv = *(const float4*)(bb + lane * 4);
  ushort4 o;
  o.x = f2bf((xv.x - mean) * rstd * gv.x + bv.x);
  o.y = f2bf((xv.y - mean) * rstd * gv.y + bv.y);
  o.z = f2bf((xv.z - mean) * rstd * gv.z + bv.z);
  o.w = f2bf((xv.w - mean) * rstd * gv.w + bv.w);
  *(ushort4*)(x16 + row * 256 + lane * 4) = o;
}

// ---------------- K/V projection GEMM (m97-style 128x128, BK=64) ----------------
__global__ void __launch_bounds__(256) kv_gemm(
    const unsigned short* __restrict__ x16, const unsigned short* __restrict__ Bkv,
    unsigned short* __restrict__ KV) {
  __shared__ __align__(16) unsigned short As[128 * 64];
  __shared__ __align__(16) unsigned short Bs[128 * 64];
  const int m0 = blockIdx.x * 128;
  const int n0 = blockIdx.y * 128;
  const int t = threadIdx.x;
  const int lane = t & 63, wv = t >> 6;
  const int wm = (wv & 1) * 64, wn = (wv >> 1) * 64;
  const int l15 = lane & 15, l4 = lane >> 4;
  f32x4 acc[4][4];
#pragma unroll
  for (int mi = 0; mi < 4; ++mi)
#pragma unroll
    for (int ni = 0; ni < 4; ++ni) {
      acc[mi][ni][0] = 0.f; acc[mi][ni][1] = 0.f;
      acc[mi][ni][2] = 0.f; acc[mi][ni][3] = 0.f;
    }
  const int sr = t >> 3, sc = t & 7;
  for (int kk = 0; kk < 4; ++kk) {
    const int kb = kk * 64;
#pragma unroll
    for (int i = 0; i < 4; ++i) {
      const unsigned short* ga = x16 + (size_t)(m0 + i * 32 + sr) * 256 + kb + sc * 8;
      GLDS16(ga, &As[(i * 32 + sr) * 64 + sc * 8]);
    }
#pragma unroll
    for (int i = 0; i < 4; ++i) {
      const unsigned short* gb = Bkv + (size_t)(n0 + i * 32 + sr) * 256 + kb + sc * 8;
      GLDS16(gb, &Bs[(i * 32 + sr) * 64 + sc * 8]);
    }
    asm volatile("s_waitcnt vmcnt(0)" ::: "memory");
    __syncthreads();
#pragma unroll
    for (int kc = 0; kc < 2; ++kc) {
      bf16x8 af[4], bfr[4];
#pragma unroll
      for (int mi = 0; mi < 4; ++mi)
        af[mi] = *(const bf16x8*)&As[(wm + mi * 16 + l15) * 64 + kc * 32 + l4 * 8];
#pragma unroll
      for (int ni = 0; ni < 4; ++ni)
        bfr[ni] = *(const bf16x8*)&Bs[(wn + ni * 16 + l15) * 64 + kc * 32 + l4 * 8];
#pragma unroll
      for (int mi = 0; mi < 4; ++mi)
#pragma unroll
        for (int ni = 0; ni < 4; ++ni)
          acc[mi][ni] = __builtin_amdgcn_mfma_f32_16x16x32_bf16(
              af[mi], bfr[ni], acc[mi][ni], 0, 0, 0);
    }
    __syncthreads();
  }
#pragma unroll
  for (int mi = 0; mi < 4; ++mi) {
#pragma unroll
    for (int r = 0; r < 4; ++r) {
      const int gm = m0 + wm + mi * 16 + l4 * 4 + r;
      unsigned short* dst = KV + (size_t)gm * 512 + n0 + wn + l15;
#pragma unroll
      for (int ni = 0; ni < 4; ++ni) dst[ni * 16] = f2bf(acc[mi][ni][r]);
    }
  }
}

// ---------------- q projection: LN(fillers) @ Wq^T -> zero-padded qtil bf16 ----------------
__global__ void __launch_bounds__(256) qproj_kernel(
    const float* __restrict__ fill, const float* __restrict__ Wqt,
    const float* __restrict__ g, const float* __restrict__ bb,
    unsigned short* __restrict__ qtil) {
  const int bi = blockIdx.x;  // b*8 + i
  const int t = threadIdx.x;
  const int wv = t >> 6, lane = t & 63;
  __shared__ float f[256];
  __shared__ float red[8];
  const float x = fill[bi * 256 + t];
  float s = x, sq = x * x;
#pragma unroll
  for (int m = 1; m < 64; m <<= 1) {
    s += __shfl_xor(s, m);
    sq += __shfl_xor(sq, m);
  }
  if (lane == 0) {
    red[wv] = s;
    red[4 + wv] = sq;
  }
  __syncthreads();
  const float S = red[0] + red[1] + red[2] + red[3];
  const float SQ = red[4] + red[5] + red[6] + red[7];
  const float mean = S * (1.f / 256.f);
  const float var = SQ * (1.f / 256.f) - mean * mean;
  const float rstd = rsqrtf(var + 1e-5f);
  f[t] = (x - mean) * rstd * g[t] + bb[t];
  __syncthreads();
  float acc = 0.f;
  for (int k = 0; k < 256; ++k) acc = fmaf(f[k], Wqt[k * 256 + t], acc);
  // qtil[b*32 + i*4 + hp][t] = (hp == t>>6) ? q : 0   (zero-padded A operand)
  const int b = bi >> 3, i = bi & 7, h = t >> 6;
  const unsigned short val = f2bf(acc);
#pragma unroll
  for (int hp = 0; hp < 4; ++hp)
    qtil[(size_t)(b * 32 + i * 4 + hp) * 256 + t] = (hp == h) ? val : (unsigned short)0;
}

// ---------------- attention pass: MFMA QK^T + C-layout softmax + V-accum ----------------
// grid 1024 = 32 b x 32 chunks(128 j); block 256 = 4 waves (each owns 32 j cols).
__global__ void __launch_bounds__(256) attn_pass(
    const unsigned short* __restrict__ KV, const unsigned short* __restrict__ qtil,
    float* __restrict__ partials, float* __restrict__ attn_out, int write_attn) {
  const int bid = blockIdx.x;
  const int b = bid >> 5, c = bid & 31;
  const int t = threadIdx.x;
  const int wv = t >> 6, lane = t & 63;
  const int l15 = lane & 15, lq = lane >> 4;
  const int j0 = c * 128;
  const int n0 = wv * 32;  // wave's 32-column slice

  __shared__ unsigned short P[32 * 130];  // attn bf16, stride 130 (bank: sh+j/2)
  __shared__ float uacc[32 * 65];         // stride 65 (bank: sh+x, 2-way free)
  __shared__ float sred[4 * 32];

  // ---- phase 1: dots = qtil @ K^T  (M=32, N=32/wave, K=256) ----
  f32x4 acc[2][2];
#pragma unroll
  for (int mt = 0; mt < 2; ++mt)
#pragma unroll
    for (int nt = 0; nt < 2; ++nt) {
      acc[mt][nt][0] = 0.f; acc[mt][nt][1] = 0.f;
      acc[mt][nt][2] = 0.f; acc[mt][nt][3] = 0.f;
    }
  const unsigned short* Qb = qtil + (size_t)b * 32 * 256;
  const unsigned short* Kb = KV + ((size_t)b * N_ + j0 + n0) * 512;
#pragma unroll
  for (int ks = 0; ks < 8; ++ks) {
    const bf16x8 a0 = *(const bf16x8*)(Qb + (size_t)(l15)*256 + ks * 32 + lq * 8);
    const bf16x8 a1 = *(const bf16x8*)(Qb + (size_t)(16 + l15) * 256 + ks * 32 + lq * 8);
#pragma unroll
    for (int nt = 0; nt < 2; ++nt) {
      const bf16x8 bf = *(const bf16x8*)(Kb + (size_t)(nt * 16 + l15) * 512 + ks * 32 + lq * 8);
      acc[0][nt] = __builtin_amdgcn_mfma_f32_16x16x32_bf16(a0, bf, acc[0][nt], 0, 0, 0);
      acc[1][nt] = __builtin_amdgcn_mfma_f32_16x16x32_bf16(a1, bf, acc[1][nt], 0, 0, 0);
    }
  }

  // ---- phase 2: softmax over sh per column; P->LDS; ssum partials; attn_out ----
  // C layout: col j = base+nt*16+l15 ; row sh = mt*16 + lq*4 + r
  float srow[8];
#pragma unroll
  for (int i = 0; i < 8; ++i) srow[i] = 0.f;
#pragma unroll
  for (int nt = 0; nt < 2; ++nt) {
    float lv[8];
#pragma unroll
    for (int mt = 0; mt < 2; ++mt)
#pragma unroll
      for (int r = 0; r < 4; ++r) lv[mt * 4 + r] = acc[mt][nt][r] * SCALE_;
    float mx = lv[0];
#pragma unroll
    for (int i = 1; i < 8; ++i) mx = fmaxf(mx, lv[i]);
    mx = fmaxf(mx, __shfl_xor(mx, 16));
    mx = fmaxf(mx, __shfl_xor(mx, 32));
    float e[8];
    float cs = 0.f;
#pragma unroll
    for (int i = 0; i < 8; ++i) {
      e[i] = __expf(lv[i] - mx);
      cs += e[i];
    }
    cs += __shfl_xor(cs, 16);
    cs += __shfl_xor(cs, 32);
    const float inv = 1.f / cs;
    const int col = n0 + nt * 16 + l15;
#pragma unroll
    for (int mt = 0; mt < 2; ++mt)
#pragma unroll
      for (int r = 0; r < 4; ++r) {
        const float a = e[mt * 4 + r] * inv;
        srow[mt * 4 + r] += a;
        P[(mt * 16 + lq * 4 + r) * 130 + col] = f2bf(a);
      }
    if (write_attn) {
#pragma unroll
      for (int mt = 0; mt < 2; ++mt) {
        const float ao =
            (e[mt * 4 + 0] + e[mt * 4 + 1] + e[mt * 4 + 2] + e[mt * 4 + 3]) * inv * 0.25f;
        attn_out[((size_t)b * NF_ + mt * 4 + lq) * N_ + j0 + col] = ao;
      }
    }
  }
#pragma unroll
  for (int k = 1; k <= 8; k <<= 1)
#pragma unroll
    for (int i = 0; i < 8; ++i) srow[i] += __shfl_xor(srow[i], k);
  if (l15 == 0) {
#pragma unroll
    for (int mt = 0; mt < 2; ++mt)
#pragma unroll
      for (int r = 0; r < 4; ++r)
        sred[wv * 32 + mt * 16 + lq * 4 + r] = srow[mt * 4 + r];
  }
  for (int x = t; x < 32 * 65; x += 256) uacc[x] = 0.f;
  __syncthreads();

  // ---- phase 3: upd[sh][d] += attn * V ----
  const int sh = lane & 31, half = lane >> 5, h = sh & 3;
  float upd[32];
#pragma unroll
  for (int x = 0; x < 32; ++x) upd[x] = 0.f;
  const unsigned short* Vrow =
      KV + ((size_t)b * N_ + j0 + n0) * 512 + 256 + h * 64 + half * 32;
  for (int jj = 0; jj < 32; ++jj) {
    const float a = b2f(P[sh * 130 + n0 + jj]);
    uint4 vw[4];
#pragma unroll
    for (int x = 0; x < 4; ++x) vw[x] = *(const uint4*)(Vrow + jj * 512 + x * 8);
#pragma unroll
    for (int x = 0; x < 4; ++x) {
      upd[x * 8 + 0] = fmaf(a, bflo(vw[x].x), upd[x * 8 + 0]);
      upd[x * 8 + 1] = fmaf(a, bfhi(vw[x].x), upd[x * 8 + 1]);
      upd[x * 8 + 2] = fmaf(a, bflo(vw[x].y), upd[x * 8 + 2]);
      upd[x * 8 + 3] = fmaf(a, bfhi(vw[x].y), upd[x * 8 + 3]);
      upd[x * 8 + 4] = fmaf(a, bflo(vw[x].z), upd[x * 8 + 4]);
      upd[x * 8 + 5] = fmaf(a, bfhi(vw[x].z), upd[x * 8 + 5]);
      upd[x * 8 + 6] = fmaf(a, bflo(vw[x].w), upd[x * 8 + 6]);
      upd[x * 8 + 7] = fmaf(a, bfhi(vw[x].w), upd[x * 8 + 7]);
    }
  }

  // ---- phase 4: block combine (stride-65 => 2-way banks = free) ----
  for (int w = 0; w < 4; ++w) {
    if (wv == w) {
#pragma unroll
      for (int x = 0; x < 32; ++x) uacc[sh * 65 + half * 32 + x] += upd[x];
    }
    __syncthreads();
  }
  float* Pp = partials + (size_t)bid * 2080;
  for (int x = t; x < 2048; x += 256) Pp[x] = uacc[(x >> 6) * 65 + (x & 63)];
  if (t < 32) Pp[2048 + t] = sred[t] + sred[32 + t] + sred[64 + t] + sred[96 + t];
}

// ---------------- GRU: partial-reduce + updates + GEMV + gates ----------------
__global__ void __launch_bounds__(256) gru_kernel(
    const float* __restrict__ partials, const float* __restrict__ prev,
    const unsigned short* __restrict__ Wcat, const float* __restrict__ bih,
    const float* __restrict__ bhh, float* __restrict__ out) {
  const int bi = blockIdx.x;  // b*8 + i
  const int b = bi >> 3;
  const int t = threadIdx.x;
  const int h = t >> 6;
  const int sh = (bi & 7) * 4 + h;
  __shared__ float u[256], pv[256];
  float raw = 0.f, s = 0.f;
  for (int cc = 0; cc < 32; ++cc) {
    const float* Pp = partials + (size_t)(b * 32 + cc) * 2080;
    raw += Pp[sh * 64 + (t & 63)];
    s += Pp[2048 + sh];
  }
  const float uu = raw / (s + (float)N_ * EPS_);
  u[t] = uu;
  pv[t] = prev[bi * 256 + t];
  __syncthreads();
  float a0 = bih[t], a1 = bih[256 + t], a2 = bih[512 + t];
  float a3 = bhh[t], a4 = bhh[256 + t], a5 = bhh[512 + t];
  for (int k = 0; k < 256; ++k) {
    const float uk = u[k], pk = pv[k];
    const unsigned short* wr = Wcat + k * 1536;
    a0 = fmaf(uk, b2f(wr[t]), a0);
    a1 = fmaf(uk, b2f(wr[256 + t]), a1);
    a2 = fmaf(uk, b2f(wr[512 + t]), a2);
    a3 = fmaf(pk, b2f(wr[768 + t]), a3);
    a4 = fmaf(pk, b2f(wr[1024 + t]), a4);
    a5 = fmaf(pk, b2f(wr[1280 + t]), a5);
  }
  const float r = 1.f / (1.f + __expf(-(a0 + a3)));
  const float z = 1.f / (1.f + __expf(-(a1 + a4)));
  const float n = tanhf(a2 + r * a5);
  out[bi * 256 + t] = (1.f - z) * n + z * pv[t];
}

extern "C" void kernel_launch(void* const* d_in, const int* in_sizes, int n_in,
                              void* d_out, int out_size, void* d_ws, size_t ws_size,
                              hipStream_t stream) {
  (void)in_sizes; (void)n_in; (void)out_size; (void)ws_size;
  const float* inputs = (const float*)d_in[0];
  const float* cond = (const float*)d_in[1];
  const float* Wq = (const float*)d_in[2];
  const float* Wk = (const float*)d_in[3];
  const float* Wv = (const float*)d_in[4];
  const float* Wih = (const float*)d_in[5];
  const float* Whh = (const float*)d_in[6];
  const float* bih = (const float*)d_in[7];
  const float* bhh = (const float*)d_in[8];
  const float* lng = (const float*)d_in[9];
  const float* lnb = (const float*)d_in[10];
  const float* lfg = (const float*)d_in[11];
  const float* lfb = (const float*)d_in[12];
  float* out = (float*)d_out;

  char* ws = (char*)d_ws;
  unsigned short* Bkv = (unsigned short*)(ws);                      // 256 KiB
  float* Wqt = (float*)(ws + 262144);                               // 256 KiB
  unsigned short* Wcat = (unsigned short*)(ws + 524288);            // 768 KiB
  unsigned short* x16 = (unsigned short*)(ws + 1310720);            // 64 MiB
  unsigned short* KV = (unsigned short*)(ws + 1310720 + 67108864);  // 128 MiB
  // Aliased into x16's region (x16 dead after kv_gemm):
  unsigned short* qtil = (unsigned short*)(ws + 1310720);           // 512 KiB
  float* fillA = (float*)(ws + 1310720 + 524288);                   // 256 KiB
  float* fillB = fillA + 65536;                                     // 256 KiB
  float* partials = fillB + 65536;                                  // 8.5 MiB

  hipLaunchKernelGGL(prep_kernel, dim3(2304), dim3(256), 0, stream,
                     Wq, Wk, Wv, Wih, Whh, Bkv, Wqt, Wcat);
  hipLaunchKernelGGL(ln_in_kernel, dim3(32768), dim3(256), 0, stream,
                     inputs, lng, lnb, x16);
  hipLaunchKernelGGL(kv_gemm, dim3(1024, 4), dim3(256), 0, stream, x16, Bkv, KV);

  const float* src = cond;
  float* attn_out = out + 65536;
  for (int it = 0; it < 3; ++it) {
    float* dst = (it == 0) ? fillA : (it == 1) ? fillB : out;  // last iter -> slots
    hipLaunchKernelGGL(qproj_kernel, dim3(256), dim3(256), 0, stream,
                       src, Wqt, lfg, lfb, qtil);
    hipLaunchKernelGGL(attn_pass, dim3(1024), dim3(256), 0, stream,
                       KV, qtil, partials, attn_out, (it == 2) ? 1 : 0);
    hipLaunchKernelGGL(gru_kernel, dim3(256), dim3(256), 0, stream,
                       partials, src, Wcat, bih, bhh, dst);
    src = dst;
  }
}